// Round 1
// baseline (1425.927 us; speedup 1.0000x reference)
//
#include <hip/hip_runtime.h>
#include <math.h>

// Problem constants
// B=16, L=144, D=512, H=8, DH=64, DS=64, HS=8, dsh=8, DFF=2048
// N = B*L*L = 331776 structure pairs

// ---------------- K0: fold sWo into Wc ----------------
// M[t*64+e][o] = sum_c sWo[e,c]*Wc[o,c,t];  C0[o] = bc[o] + sum_{t,c} sbo[c]*Wc[o,c,t]
__global__ __launch_bounds__(256) void precompute_M(
    const float* __restrict__ sWo, const float* __restrict__ Wc,
    const float* __restrict__ sbo, const float* __restrict__ bc,
    float* __restrict__ M, float* __restrict__ C0) {
  int blk = blockIdx.x, tid = threadIdx.x;
  int t = blk >> 2;
  int e = (blk & 3) * 16 + (tid >> 4);
  int o4 = (tid & 15) * 4;
  float acc[4] = {0.f, 0.f, 0.f, 0.f};
  for (int c = 0; c < 64; ++c) {
    float a = sWo[e * 64 + c];
#pragma unroll
    for (int j = 0; j < 4; ++j) acc[j] += a * Wc[((o4 + j) * 64 + c) * 4 + t];
  }
#pragma unroll
  for (int j = 0; j < 4; ++j) M[(t * 64 + e) * 64 + o4 + j] = acc[j];
  if (blk == 0 && tid < 64) {
    float s = bc[tid];
    for (int c = 0; c < 64; ++c) {
      float sb = sbo[c];
#pragma unroll
      for (int t2 = 0; t2 < 4; ++t2) s += sb * Wc[(tid * 64 + c) * 4 + t2];
    }
    C0[tid] = s;
  }
}

// ---------------- K1: LayerNorm over 512 ----------------
__global__ __launch_bounds__(256) void ln512(
    const float* __restrict__ x, const float* __restrict__ g,
    const float* __restrict__ bb, float* __restrict__ out) {
  int row = blockIdx.x, tid = threadIdx.x;
  const float* xr = x + (size_t)row * 512;
  float2 v = *(const float2*)&xr[tid * 2];
  float s1 = v.x + v.y;
  float s2 = v.x * v.x + v.y * v.y;
#pragma unroll
  for (int m = 32; m >= 1; m >>= 1) {
    s1 += __shfl_xor(s1, m);
    s2 += __shfl_xor(s2, m);
  }
  __shared__ float red[8];
  int wid = tid >> 6;
  if ((tid & 63) == 0) { red[wid * 2] = s1; red[wid * 2 + 1] = s2; }
  __syncthreads();
  s1 = red[0] + red[2] + red[4] + red[6];
  s2 = red[1] + red[3] + red[5] + red[7];
  float mean = s1 * (1.f / 512.f);
  float var = s2 * (1.f / 512.f) - mean * mean;
  float rs = 1.f / sqrtf(var + 1e-6f);
  int c = tid * 2;
  float2 gg = *(const float2*)&g[c];
  float2 bv = *(const float2*)&bb[c];
  float2 o;
  o.x = (v.x - mean) * rs * gg.x + bv.x;
  o.y = (v.y - mean) * rs * gg.y + bv.y;
  *(float2*)&out[(size_t)row * 512 + c] = o;
}

// ---------------- K2: generic f32 tiled GEMM ----------------
// C[M,N] = (A[M,K] @ W[K,N] + bias)*scale  [+relu] [+res]
__global__ __launch_bounds__(256) void gemm_f32(
    const float* __restrict__ A, const float* __restrict__ W,
    const float* __restrict__ bias, const float* __restrict__ res,
    float* __restrict__ C, int M, int N, int K, float scale, int relu) {
  __shared__ float At[16][68];
  __shared__ float Wt[16][64];
  int tid = threadIdx.x;
  int n0 = blockIdx.x * 64, m0 = blockIdx.y * 64;
  int tr = tid >> 4, tc = tid & 15;
  float acc[4][4] = {{0.f}};
  int am = tid >> 2, ak4 = (tid & 3) * 4;
  int wk = tid >> 4, wn4 = (tid & 15) * 4;
  for (int k0 = 0; k0 < K; k0 += 16) {
    float4 a4 = *(const float4*)&A[(size_t)(m0 + am) * K + k0 + ak4];
    float4 w4 = *(const float4*)&W[(size_t)(k0 + wk) * N + n0 + wn4];
    At[ak4 + 0][am] = a4.x; At[ak4 + 1][am] = a4.y;
    At[ak4 + 2][am] = a4.z; At[ak4 + 3][am] = a4.w;
    *(float4*)&Wt[wk][wn4] = w4;
    __syncthreads();
#pragma unroll
    for (int kk = 0; kk < 16; ++kk) {
      float4 av = *(float4*)&At[kk][tr * 4];
      float4 wv = *(float4*)&Wt[kk][tc * 4];
      float ar[4] = {av.x, av.y, av.z, av.w};
      float wr[4] = {wv.x, wv.y, wv.z, wv.w};
#pragma unroll
      for (int i = 0; i < 4; ++i)
#pragma unroll
        for (int j = 0; j < 4; ++j) acc[i][j] += ar[i] * wr[j];
    }
    __syncthreads();
  }
  float b4[4] = {bias[n0 + tc * 4], bias[n0 + tc * 4 + 1],
                 bias[n0 + tc * 4 + 2], bias[n0 + tc * 4 + 3]};
#pragma unroll
  for (int i = 0; i < 4; ++i) {
    int row = m0 + tr * 4 + i;
    float4 o;
    o.x = (acc[i][0] + b4[0]) * scale;
    o.y = (acc[i][1] + b4[1]) * scale;
    o.z = (acc[i][2] + b4[2]) * scale;
    o.w = (acc[i][3] + b4[3]) * scale;
    if (relu) {
      o.x = fmaxf(o.x, 0.f); o.y = fmaxf(o.y, 0.f);
      o.z = fmaxf(o.z, 0.f); o.w = fmaxf(o.w, 0.f);
    }
    if (res) {
      float4 r4 = *(const float4*)&res[(size_t)row * N + n0 + tc * 4];
      o.x += r4.x; o.y += r4.y; o.z += r4.z; o.w += r4.w;
    }
    *(float4*)&C[(size_t)row * N + n0 + tc * 4] = o;
  }
}

// ---------------- K3: fused structure pipeline ----------------
__device__ __forceinline__ void sgemm_qkv(
    const float (&At)[64][64], float (&Wl)[64][64], float (&outb)[64][64],
    const float* __restrict__ W, const float* __restrict__ bias, float scale,
    int tid) {
  __syncthreads();
  for (int i = tid; i < 1024; i += 256) {
    int c = i >> 4, o4 = (i & 15) << 2;
    *(float4*)&Wl[c][o4] = *(const float4*)&W[c * 64 + o4];
  }
  __syncthreads();
  int tr = tid >> 4, tc = tid & 15;
  float acc[4][4] = {{0.f}};
#pragma unroll 8
  for (int c = 0; c < 64; ++c) {
    float4 a4 = *(const float4*)&At[c][tr * 4];
    float4 w4 = *(float4*)&Wl[c][tc * 4];
    float ar[4] = {a4.x, a4.y, a4.z, a4.w};
    float wr[4] = {w4.x, w4.y, w4.z, w4.w};
#pragma unroll
    for (int i = 0; i < 4; ++i)
#pragma unroll
      for (int j = 0; j < 4; ++j) acc[i][j] += ar[i] * wr[j];
  }
  float b4[4] = {bias[tc * 4], bias[tc * 4 + 1], bias[tc * 4 + 2],
                 bias[tc * 4 + 3]};
#pragma unroll
  for (int i = 0; i < 4; ++i) {
    float4 o;
    o.x = (acc[i][0] + b4[0]) * scale;
    o.y = (acc[i][1] + b4[1]) * scale;
    o.z = (acc[i][2] + b4[2]) * scale;
    o.w = (acc[i][3] + b4[3]) * scale;
    *(float4*)&outb[tr * 4 + i][tc * 4] = o;
  }
}

__global__ __launch_bounds__(256) void struct_pipeline(
    const float* __restrict__ S, const float* __restrict__ sWq,
    const float* __restrict__ sbq, const float* __restrict__ sWk,
    const float* __restrict__ sbk, const float* __restrict__ sWv,
    const float* __restrict__ sbv, const float* __restrict__ Mw,
    const float* __restrict__ C0, const float* __restrict__ gs,
    const float* __restrict__ bsv, float* __restrict__ Rout) {
  __shared__ float At[64][64];  // s^T, later ctx^T  [channel][row=n*4+t]
  __shared__ float Wl[64][64];
  __shared__ float qs[64][64];
  __shared__ float ks[64][64];
  __shared__ float vs[64][64];
  int tid = threadIdx.x;
  int nb = blockIdx.x;
  int b = nb / 1296;
  int pbase = (nb - b * 1296) * 16;
  // phase 0: load 16 pairs' [4,64] blocks, transposed into At[c][row]
  for (int i = tid; i < 1024; i += 256) {
    int nl = i >> 6, t = (i >> 4) & 3, c4 = (i & 15) << 2;
    size_t gidx = ((size_t)((pbase + nl) * 4 + t) * 16 + b) * 64 + c4;
    float4 a = *(const float4*)&S[gidx];
    int r = nl * 4 + t;
    At[c4 + 0][r] = a.x; At[c4 + 1][r] = a.y;
    At[c4 + 2][r] = a.z; At[c4 + 3][r] = a.w;
  }
  sgemm_qkv(At, Wl, qs, sWq, sbq, 0.35355339059327373f, tid);
  sgemm_qkv(At, Wl, ks, sWk, sbk, 1.f, tid);
  sgemm_qkv(At, Wl, vs, sWv, sbv, 1.f, tid);
  __syncthreads();
  // sub-attention: one thread per (n, head); 8 heads, dsh=8, seqlen 4
  if (tid < 128) {
    int n = tid >> 3, h = tid & 7;
    float qq[4][8], kk[4][8], vv[4][8];
#pragma unroll
    for (int t = 0; t < 4; ++t)
#pragma unroll
      for (int e = 0; e < 8; ++e) {
        qq[t][e] = qs[n * 4 + t][h * 8 + e];
        kk[t][e] = ks[n * 4 + t][h * 8 + e];
        vv[t][e] = vs[n * 4 + t][h * 8 + e];
      }
#pragma unroll
    for (int i2 = 0; i2 < 4; ++i2) {
      float s[4];
#pragma unroll
      for (int j = 0; j < 4; ++j) {
        float a = 0.f;
#pragma unroll
        for (int e = 0; e < 8; ++e) a += qq[i2][e] * kk[j][e];
        s[j] = a;
      }
      float mx = fmaxf(fmaxf(s[0], s[1]), fmaxf(s[2], s[3]));
      float p[4];
      float sum = 0.f;
#pragma unroll
      for (int j = 0; j < 4; ++j) { p[j] = __expf(s[j] - mx); sum += p[j]; }
      float inv = 1.f / sum;
#pragma unroll
      for (int e = 0; e < 8; ++e) {
        float c2 = p[0] * vv[0][e] + p[1] * vv[1][e] + p[2] * vv[2][e] +
                   p[3] * vv[3][e];
        At[h * 8 + e][n * 4 + i2] = c2 * inv;  // ctx^T
      }
    }
  }
  __syncthreads();
  // conv (folded sWo@Wc): out[n,o] = sum_t sum_e ctx[n,t,e]*M[(t*64+e)*64+o]
  int nloc = tid >> 4, o4 = (tid & 15) << 2;
  float acc4[4] = {0.f, 0.f, 0.f, 0.f};
  for (int t = 0; t < 4; ++t) {
    for (int i = tid; i < 1024; i += 256) {
      int c = i >> 4, oo = (i & 15) << 2;
      *(float4*)&Wl[c][oo] = *(const float4*)&Mw[(size_t)(t * 64 + c) * 64 + oo];
    }
    __syncthreads();
#pragma unroll 8
    for (int c = 0; c < 64; ++c) {
      float a = At[c][nloc * 4 + t];
      float4 w4 = *(float4*)&Wl[c][o4];
      acc4[0] += a * w4.x; acc4[1] += a * w4.y;
      acc4[2] += a * w4.z; acc4[3] += a * w4.w;
    }
    __syncthreads();
  }
  // +C0, ReLU, LayerNorm(64) within 16-lane group, write R
  float co[4];
#pragma unroll
  for (int j = 0; j < 4; ++j) co[j] = fmaxf(acc4[j] + C0[o4 + j], 0.f);
  float s1 = co[0] + co[1] + co[2] + co[3];
  float s2 = co[0] * co[0] + co[1] * co[1] + co[2] * co[2] + co[3] * co[3];
#pragma unroll
  for (int m = 8; m >= 1; m >>= 1) {
    s1 += __shfl_xor(s1, m);
    s2 += __shfl_xor(s2, m);
  }
  float mean = s1 * (1.f / 64.f);
  float var = s2 * (1.f / 64.f) - mean * mean;
  float rs = 1.f / sqrtf(var + 1e-6f);
  size_t ng = (size_t)nb * 16 + nloc;
  float4 o;
  o.x = (co[0] - mean) * rs * gs[o4 + 0] + bsv[o4 + 0];
  o.y = (co[1] - mean) * rs * gs[o4 + 1] + bsv[o4 + 1];
  o.z = (co[2] - mean) * rs * gs[o4 + 2] + bsv[o4 + 2];
  o.w = (co[3] - mean) * rs * gs[o4 + 3] + bsv[o4 + 3];
  *(float4*)&Rout[ng * 64 + o4] = o;
}

// ---------------- K4: relation-biased main attention ----------------
// one block per (b,i): scores[h][j] = q[h]·(k[b,h,j]+R[b,i,j]) ; mask ; softmax ;
// ctx[h][d] = sum_j p*(v[b,h,j,d]+R[b,i,j,d])
__global__ __launch_bounds__(256) void attn_main(
    const float* __restrict__ q, const float* __restrict__ k,
    const float* __restrict__ v, const float* __restrict__ R,
    const int* __restrict__ msk, float* __restrict__ ctx_out) {
  const int L = 144;
  int blk = blockIdx.x;
  int b = blk / L, i = blk - b * L;
  int tid = threadIdx.x;
  __shared__ float RlT[64][149];  // R transposed [d][j], pad 149 (2-way max)
  __shared__ float scl[8][144];
  __shared__ float q8[512];
  const float* Rrow = R + ((size_t)(b * L + i)) * L * 64;
  for (int idx = tid; idx < 144 * 16; idx += 256) {
    int j = idx >> 4, d4 = (idx & 15) * 4;
    float4 r4 = *(const float4*)&Rrow[(size_t)j * 64 + d4];
    RlT[d4 + 0][j] = r4.x; RlT[d4 + 1][j] = r4.y;
    RlT[d4 + 2][j] = r4.z; RlT[d4 + 3][j] = r4.w;
  }
  if (tid < 128)
    *(float4*)&q8[tid * 4] =
        *(const float4*)&q[(size_t)(b * L + i) * 512 + tid * 4];
  __syncthreads();
  const float* kb = k + (size_t)b * L * 512;
  const int* mrow = msk + (size_t)(b * L + i) * 144;
  for (int idx = tid; idx < 8 * 144; idx += 256) {
    int h = idx / 144, j = idx - h * 144;
    const float* kr = kb + (size_t)j * 512 + h * 64;
    float s = 0.f;
#pragma unroll
    for (int d0 = 0; d0 < 64; d0 += 4) {
      float4 kv = *(const float4*)&kr[d0];
      s += q8[h * 64 + d0 + 0] * (kv.x + RlT[d0 + 0][j]);
      s += q8[h * 64 + d0 + 1] * (kv.y + RlT[d0 + 1][j]);
      s += q8[h * 64 + d0 + 2] * (kv.z + RlT[d0 + 2][j]);
      s += q8[h * 64 + d0 + 3] * (kv.w + RlT[d0 + 3][j]);
    }
    if (mrow[j] != 0) s = -1e18f;
    scl[h][j] = s;
  }
  __syncthreads();
  int h = tid >> 5, l = tid & 31;
  float m = -3.4e38f;
  for (int j = l; j < 144; j += 32) m = fmaxf(m, scl[h][j]);
#pragma unroll
  for (int mm = 16; mm >= 1; mm >>= 1) m = fmaxf(m, __shfl_xor(m, mm));
  float sum = 0.f;
  for (int j = l; j < 144; j += 32) {
    float p = __expf(scl[h][j] - m);
    scl[h][j] = p;
    sum += p;
  }
#pragma unroll
  for (int mm = 16; mm >= 1; mm >>= 1) sum += __shfl_xor(sum, mm);
  float inv = 1.f / sum;
  __syncthreads();
  int d0 = l * 2;
  float a0 = 0.f, a1 = 0.f;
  const float* vb = v + (size_t)b * L * 512 + h * 64 + d0;
  for (int j = 0; j < 144; ++j) {
    float p = scl[h][j];
    float2 vv = *(const float2*)&vb[(size_t)j * 512];
    a0 += p * (vv.x + RlT[d0][j]);
    a1 += p * (vv.y + RlT[d0 + 1][j]);
  }
  float2 o;
  o.x = a0 * inv;
  o.y = a1 * inv;
  *(float2*)&ctx_out[(size_t)(b * L + i) * 512 + h * 64 + d0] = o;
}

// ---------------- launch ----------------
extern "C" void kernel_launch(void* const* d_in, const int* in_sizes, int n_in,
                              void* d_out, int out_size, void* d_ws,
                              size_t ws_size, hipStream_t stream) {
  (void)in_sizes; (void)n_in; (void)out_size; (void)ws_size;
  const float* inputs = (const float*)d_in[0];
  const float* structure = (const float*)d_in[1];
  const int* mask = (const int*)d_in[2];
  const float* g_att = (const float*)d_in[3];
  const float* b_att = (const float*)d_in[4];
  const float* Wq = (const float*)d_in[5];
  const float* bq = (const float*)d_in[6];
  const float* Wk = (const float*)d_in[7];
  const float* bk = (const float*)d_in[8];
  const float* Wv = (const float*)d_in[9];
  const float* bv = (const float*)d_in[10];
  const float* Wo = (const float*)d_in[11];
  const float* bo = (const float*)d_in[12];
  const float* sWq = (const float*)d_in[13];
  const float* sbq = (const float*)d_in[14];
  const float* sWk = (const float*)d_in[15];
  const float* sbk = (const float*)d_in[16];
  const float* sWv = (const float*)d_in[17];
  const float* sbv = (const float*)d_in[18];
  const float* sWo = (const float*)d_in[19];
  const float* sbo = (const float*)d_in[20];
  const float* Wc = (const float*)d_in[21];
  const float* bc = (const float*)d_in[22];
  const float* g_s = (const float*)d_in[23];
  const float* b_s = (const float*)d_in[24];
  const float* g_ffn = (const float*)d_in[25];
  const float* b_ffn = (const float*)d_in[26];
  const float* W1 = (const float*)d_in[27];
  const float* b1 = (const float*)d_in[28];
  const float* W2 = (const float*)d_in[29];
  const float* b2 = (const float*)d_in[30];

  float* ws = (float*)d_ws;
  const size_t TOK = 2304ull * 512ull;  // 1179648
  float* xn = ws;            // x_norm, later ctx
  float* qw = xn + TOK;      // q, later x_norm2 (FFN)
  float* kw = qw + TOK;
  float* vw = kw + TOK;
  float* xw = vw + TOK;      // post-attention residual x
  float* Rw = xw + TOK;      // R [B,L,L,64] (21233664), later FFN hidden
  float* Mw = Rw + 21233664ull;
  float* C0w = Mw + 16384;
  float* out = (float*)d_out;

  precompute_M<<<16, 256, 0, stream>>>(sWo, Wc, sbo, bc, Mw, C0w);
  ln512<<<2304, 256, 0, stream>>>(inputs, g_att, b_att, xn);
  gemm_f32<<<dim3(8, 36), 256, 0, stream>>>(xn, Wq, bq, nullptr, qw, 2304, 512,
                                            512, 0.125f, 0);
  gemm_f32<<<dim3(8, 36), 256, 0, stream>>>(xn, Wk, bk, nullptr, kw, 2304, 512,
                                            512, 1.f, 0);
  gemm_f32<<<dim3(8, 36), 256, 0, stream>>>(xn, Wv, bv, nullptr, vw, 2304, 512,
                                            512, 1.f, 0);
  struct_pipeline<<<20736, 256, 0, stream>>>(structure, sWq, sbq, sWk, sbk,
                                             sWv, sbv, Mw, C0w, g_s, b_s, Rw);
  attn_main<<<2304, 256, 0, stream>>>(qw, kw, vw, Rw, mask, xn);
  gemm_f32<<<dim3(8, 36), 256, 0, stream>>>(xn, Wo, bo, inputs, xw, 2304, 512,
                                            512, 1.f, 0);
  ln512<<<2304, 256, 0, stream>>>(xw, g_ffn, b_ffn, qw);
  gemm_f32<<<dim3(32, 36), 256, 0, stream>>>(qw, W1, b1, nullptr, Rw, 2304,
                                             2048, 512, 1.f, 1);
  gemm_f32<<<dim3(8, 36), 256, 0, stream>>>(Rw, W2, b2, xw, out, 2304, 512,
                                            2048, 1.f, 0);
}

// Round 2
// 804.823 us; speedup vs baseline: 1.7717x; 1.7717x over previous
//
#include <hip/hip_runtime.h>
#include <math.h>

// B=16, L=144, D=512, H=8, DH=64, DS=64, HS=8, dsh=8, DFF=2048
// N = B*L*L = 331776 structure pairs; 20736 pairs per b; 648 blocks/b (32 pairs each)

typedef __bf16 bf16_t;
typedef __bf16 bf16x8 __attribute__((ext_vector_type(8)));
typedef float f32x4 __attribute__((ext_vector_type(4)));

// ---------------- K0: precompute transposed bf16 weights ----------------
// WT[3][64][64]: WT[m][oc][ic] = sW{q,k,v}[ic][oc]  (bf16)
// M2T[64][256]:  M2T[o][t*64+e] = sum_c sWo[e][c]*Wc[o][c][t]  (bf16)
// C0[o] = bc[o] + sum_{t,c} sbo[c]*Wc[o][c][t]  (f32)
__global__ __launch_bounds__(256) void precompute(
    const float* __restrict__ sWq, const float* __restrict__ sWk,
    const float* __restrict__ sWv, const float* __restrict__ sWo,
    const float* __restrict__ sbo, const float* __restrict__ Wc,
    const float* __restrict__ bc, bf16_t* __restrict__ WT,
    bf16_t* __restrict__ M2T, float* __restrict__ C0) {
  int blk = blockIdx.x, tid = threadIdx.x;
  if (blk == 16) {
    for (int idx = tid; idx < 4096; idx += 256) {
      int oc = idx >> 6, ic = idx & 63;
      WT[idx] = (__bf16)sWq[ic * 64 + oc];
      WT[4096 + idx] = (__bf16)sWk[ic * 64 + oc];
      WT[8192 + idx] = (__bf16)sWv[ic * 64 + oc];
    }
    if (tid < 64) {
      float s = bc[tid];
      for (int c = 0; c < 64; ++c) {
        float sb = sbo[c];
#pragma unroll
        for (int t = 0; t < 4; ++t) s += sb * Wc[tid * 256 + c * 4 + t];
      }
      C0[tid] = s;
    }
  } else {
    int t = blk >> 2;
    int e = (blk & 3) * 16 + (tid >> 4);
    int o4 = (tid & 15) * 4;
    float acc[4] = {0.f, 0.f, 0.f, 0.f};
    for (int c = 0; c < 64; ++c) {
      float a = sWo[e * 64 + c];
#pragma unroll
      for (int j = 0; j < 4; ++j) acc[j] += a * Wc[(o4 + j) * 256 + c * 4 + t];
    }
#pragma unroll
    for (int j = 0; j < 4; ++j)
      M2T[(o4 + j) * 256 + t * 64 + e] = (__bf16)acc[j];
  }
}

// ---------------- K1: LayerNorm over 512 ----------------
__global__ __launch_bounds__(256) void ln512(
    const float* __restrict__ x, const float* __restrict__ g,
    const float* __restrict__ bb, float* __restrict__ out) {
  int row = blockIdx.x, tid = threadIdx.x;
  const float* xr = x + (size_t)row * 512;
  float2 v = *(const float2*)&xr[tid * 2];
  float s1 = v.x + v.y;
  float s2 = v.x * v.x + v.y * v.y;
#pragma unroll
  for (int m = 32; m >= 1; m >>= 1) {
    s1 += __shfl_xor(s1, m);
    s2 += __shfl_xor(s2, m);
  }
  __shared__ float red[8];
  int wid = tid >> 6;
  if ((tid & 63) == 0) { red[wid * 2] = s1; red[wid * 2 + 1] = s2; }
  __syncthreads();
  s1 = red[0] + red[2] + red[4] + red[6];
  s2 = red[1] + red[3] + red[5] + red[7];
  float mean = s1 * (1.f / 512.f);
  float var = s2 * (1.f / 512.f) - mean * mean;
  float rs = 1.f / sqrtf(var + 1e-6f);
  int c = tid * 2;
  float2 gg = *(const float2*)&g[c];
  float2 bv = *(const float2*)&bb[c];
  float2 o;
  o.x = (v.x - mean) * rs * gg.x + bv.x;
  o.y = (v.y - mean) * rs * gg.y + bv.y;
  *(float2*)&out[(size_t)row * 512 + c] = o;
}

// ---------------- K2: generic f32 tiled GEMM ----------------
__global__ __launch_bounds__(256) void gemm_f32(
    const float* __restrict__ A, const float* __restrict__ W,
    const float* __restrict__ bias, const float* __restrict__ res,
    float* __restrict__ C, int M, int N, int K, float scale, int relu) {
  __shared__ float At[16][68];
  __shared__ float Wt[16][64];
  int tid = threadIdx.x;
  int n0 = blockIdx.x * 64, m0 = blockIdx.y * 64;
  int tr = tid >> 4, tc = tid & 15;
  float acc[4][4] = {{0.f}};
  int am = tid >> 2, ak4 = (tid & 3) * 4;
  int wk = tid >> 4, wn4 = (tid & 15) * 4;
  for (int k0 = 0; k0 < K; k0 += 16) {
    float4 a4 = *(const float4*)&A[(size_t)(m0 + am) * K + k0 + ak4];
    float4 w4 = *(const float4*)&W[(size_t)(k0 + wk) * N + n0 + wn4];
    At[ak4 + 0][am] = a4.x; At[ak4 + 1][am] = a4.y;
    At[ak4 + 2][am] = a4.z; At[ak4 + 3][am] = a4.w;
    *(float4*)&Wt[wk][wn4] = w4;
    __syncthreads();
#pragma unroll
    for (int kk = 0; kk < 16; ++kk) {
      float4 av = *(float4*)&At[kk][tr * 4];
      float4 wv = *(float4*)&Wt[kk][tc * 4];
      float ar[4] = {av.x, av.y, av.z, av.w};
      float wr[4] = {wv.x, wv.y, wv.z, wv.w};
#pragma unroll
      for (int i = 0; i < 4; ++i)
#pragma unroll
        for (int j = 0; j < 4; ++j) acc[i][j] += ar[i] * wr[j];
    }
    __syncthreads();
  }
  float b4[4] = {bias[n0 + tc * 4], bias[n0 + tc * 4 + 1],
                 bias[n0 + tc * 4 + 2], bias[n0 + tc * 4 + 3]};
#pragma unroll
  for (int i = 0; i < 4; ++i) {
    int row = m0 + tr * 4 + i;
    float4 o;
    o.x = (acc[i][0] + b4[0]) * scale;
    o.y = (acc[i][1] + b4[1]) * scale;
    o.z = (acc[i][2] + b4[2]) * scale;
    o.w = (acc[i][3] + b4[3]) * scale;
    if (relu) {
      o.x = fmaxf(o.x, 0.f); o.y = fmaxf(o.y, 0.f);
      o.z = fmaxf(o.z, 0.f); o.w = fmaxf(o.w, 0.f);
    }
    if (res) {
      float4 r4 = *(const float4*)&res[(size_t)row * N + n0 + tc * 4];
      o.x += r4.x; o.y += r4.y; o.z += r4.z; o.w += r4.w;
    }
    *(float4*)&C[(size_t)row * N + n0 + tc * 4] = o;
  }
}

// ---------------- K3: MFMA structure pipeline ----------------
// One block = 32 pairs (128 A-rows). 4 waves; wave w owns rows [w*32,w*32+32).
// QKV GEMMs: A-frags from global (regs), B-frags from precomputed WT (global).
// Sub-attention fully in registers from C-fragments (8-lane shfl reduce).
// ctx -> swizzled LDS (bf16) -> conv GEMM vs M2T -> ReLU -> LN(64) -> R.
__global__ __launch_bounds__(256) void struct_mfma(
    const float* __restrict__ S, const bf16_t* __restrict__ WT,
    const float* __restrict__ sbq, const float* __restrict__ sbk,
    const float* __restrict__ sbv, const bf16_t* __restrict__ M2T,
    const float* __restrict__ C0, const float* __restrict__ gs,
    const float* __restrict__ bsv, float* __restrict__ Rout) {
  __shared__ bf16_t A2[32 * 256];  // swizzled ctx (16KB); reused as f32 cv[32][68]
  int tid = threadIdx.x;
  int w = tid >> 6, l = tid & 63;
  int l15 = l & 15, l4 = l >> 4;
  int nb = blockIdx.x;
  int b = nb / 648;
  int p0 = (nb - b * 648) * 32;

  // ---- A-fragments from global: row r = w*32+rt*16+l15, k = kb*32+l4*8
  bf16x8 afr[2][2];
  const float* Sb = S + (size_t)p0 * 4096 + (size_t)b * 64;
#pragma unroll
  for (int rt = 0; rt < 2; ++rt)
#pragma unroll
    for (int kb = 0; kb < 2; ++kb) {
      int r = w * 32 + rt * 16 + l15;
      int k = kb * 32 + l4 * 8;
      const float* p = Sb + (size_t)r * 1024 + k;
      float4 u0 = *(const float4*)p;
      float4 u1 = *(const float4*)(p + 4);
      bf16x8 a;
      a[0] = (__bf16)u0.x; a[1] = (__bf16)u0.y;
      a[2] = (__bf16)u0.z; a[3] = (__bf16)u0.w;
      a[4] = (__bf16)u1.x; a[5] = (__bf16)u1.y;
      a[6] = (__bf16)u1.z; a[7] = (__bf16)u1.w;
      afr[rt][kb] = a;
    }

  // ---- per col-tile (16 channels = 2 heads): QKV mfma + sub-attention
#pragma unroll 1
  for (int ct = 0; ct < 4; ++ct) {
    int col = ct * 16 + l15;
    float biq = sbq[col], bik = sbk[col], biv = sbv[col];
    f32x4 aq[2], ak[2], av[2];
#pragma unroll
    for (int rt = 0; rt < 2; ++rt) {
      aq[rt] = (f32x4){biq, biq, biq, biq};
      ak[rt] = (f32x4){bik, bik, bik, bik};
      av[rt] = (f32x4){biv, biv, biv, biv};
    }
#pragma unroll
    for (int kb = 0; kb < 2; ++kb) {
      int k = kb * 32 + l4 * 8;
      bf16x8 bq8 = *(const bf16x8*)(WT + col * 64 + k);
      bf16x8 bk8 = *(const bf16x8*)(WT + 4096 + col * 64 + k);
      bf16x8 bv8 = *(const bf16x8*)(WT + 8192 + col * 64 + k);
#pragma unroll
      for (int rt = 0; rt < 2; ++rt) {
        aq[rt] = __builtin_amdgcn_mfma_f32_16x16x32_bf16(afr[rt][kb], bq8,
                                                         aq[rt], 0, 0, 0);
        ak[rt] = __builtin_amdgcn_mfma_f32_16x16x32_bf16(afr[rt][kb], bk8,
                                                         ak[rt], 0, 0, 0);
        av[rt] = __builtin_amdgcn_mfma_f32_16x16x32_bf16(afr[rt][kb], bv8,
                                                         av[rt], 0, 0, 0);
      }
    }
    // sub-attention: lane holds (pair = w*8+rt*4+l4, chan col); 8 lanes/head
#pragma unroll
    for (int rt = 0; rt < 2; ++rt) {
      float sc[4][4];
#pragma unroll
      for (int i = 0; i < 4; ++i)
#pragma unroll
        for (int j = 0; j < 4; ++j)
          sc[i][j] = (aq[rt][i] * 0.35355339059327373f) * ak[rt][j];
#pragma unroll
      for (int m = 1; m <= 4; m <<= 1)
#pragma unroll
        for (int i = 0; i < 4; ++i)
#pragma unroll
          for (int j = 0; j < 4; ++j) sc[i][j] += __shfl_xor(sc[i][j], m);
      int pair = w * 8 + rt * 4 + l4;
      int swz = (pair & 7) << 3;
#pragma unroll
      for (int i = 0; i < 4; ++i) {
        float mx = fmaxf(fmaxf(sc[i][0], sc[i][1]), fmaxf(sc[i][2], sc[i][3]));
        float e0 = __expf(sc[i][0] - mx), e1 = __expf(sc[i][1] - mx);
        float e2 = __expf(sc[i][2] - mx), e3 = __expf(sc[i][3] - mx);
        float inv = 1.f / (e0 + e1 + e2 + e3);
        float cx = (e0 * av[rt][0] + e1 * av[rt][1] + e2 * av[rt][2] +
                    e3 * av[rt][3]) * inv;
        A2[(pair << 8) + (((i << 6) + col) ^ swz)] = (__bf16)cx;
      }
    }
  }
  __syncthreads();

  // ---- conv GEMM: rows=32 pairs, K=256 (t*64+e), N=64 outputs
  int rtc = w >> 1;
  int ctbase = (w & 1) * 2;
  f32x4 acc2[2];
#pragma unroll
  for (int c = 0; c < 2; ++c) {
    float c0v = C0[(ctbase + c) * 16 + l15];
    acc2[c] = (f32x4){c0v, c0v, c0v, c0v};
  }
  int pr = rtc * 16 + l15;
  int swzr = (pr & 7) << 3;
#pragma unroll
  for (int kb = 0; kb < 8; ++kb) {
    int k = kb * 32 + l4 * 8;
    bf16x8 a2f = *(const bf16x8*)&A2[(pr << 8) + (k ^ swzr)];
#pragma unroll
    for (int c = 0; c < 2; ++c) {
      int o = (ctbase + c) * 16 + l15;
      bf16x8 bm = *(const bf16x8*)(M2T + o * 256 + k);
      acc2[c] =
          __builtin_amdgcn_mfma_f32_16x16x32_bf16(a2f, bm, acc2[c], 0, 0, 0);
    }
  }
  __syncthreads();  // all A2 reads done before overwrite
  float* cv = (float*)A2;
#pragma unroll
  for (int c = 0; c < 2; ++c) {
    int o = (ctbase + c) * 16 + l15;
#pragma unroll
    for (int j = 0; j < 4; ++j) {
      int pair = rtc * 16 + l4 * 4 + j;
      cv[pair * 68 + o] = fmaxf(acc2[c][j], 0.f);
    }
  }
  __syncthreads();

  // ---- LN(64) per pair: 8 lanes/pair, 8 ch/lane
  int pair = tid >> 3, e8 = (tid & 7) * 8;
  float4 v0 = *(float4*)&cv[pair * 68 + e8];
  float4 v1 = *(float4*)&cv[pair * 68 + e8 + 4];
  float s1 = v0.x + v0.y + v0.z + v0.w + v1.x + v1.y + v1.z + v1.w;
  float s2 = v0.x * v0.x + v0.y * v0.y + v0.z * v0.z + v0.w * v0.w +
             v1.x * v1.x + v1.y * v1.y + v1.z * v1.z + v1.w * v1.w;
#pragma unroll
  for (int m = 1; m <= 4; m <<= 1) {
    s1 += __shfl_xor(s1, m);
    s2 += __shfl_xor(s2, m);
  }
  float mean = s1 * (1.f / 64.f);
  float var = s2 * (1.f / 64.f) - mean * mean;
  float rs = 1.f / sqrtf(var + 1e-6f);
  float4 g0 = *(const float4*)&gs[e8], g1 = *(const float4*)&gs[e8 + 4];
  float4 b0 = *(const float4*)&bsv[e8], b1 = *(const float4*)&bsv[e8 + 4];
  float4 o0, o1;
  o0.x = (v0.x - mean) * rs * g0.x + b0.x;
  o0.y = (v0.y - mean) * rs * g0.y + b0.y;
  o0.z = (v0.z - mean) * rs * g0.z + b0.z;
  o0.w = (v0.w - mean) * rs * g0.w + b0.w;
  o1.x = (v1.x - mean) * rs * g1.x + b1.x;
  o1.y = (v1.y - mean) * rs * g1.y + b1.y;
  o1.z = (v1.z - mean) * rs * g1.z + b1.z;
  o1.w = (v1.w - mean) * rs * g1.w + b1.w;
  size_t base = ((size_t)b * 20736 + p0 + pair) * 64 + e8;
  *(float4*)&Rout[base] = o0;
  *(float4*)&Rout[base + 4] = o1;
}

// ---------------- K4: relation-biased main attention ----------------
__global__ __launch_bounds__(256) void attn_main(
    const float* __restrict__ q, const float* __restrict__ k,
    const float* __restrict__ v, const float* __restrict__ R,
    const int* __restrict__ msk, float* __restrict__ ctx_out) {
  const int L = 144;
  int blk = blockIdx.x;
  int b = blk / L, i = blk - b * L;
  int tid = threadIdx.x;
  __shared__ float RlT[64][149];
  __shared__ float scl[8][144];
  __shared__ float q8[512];
  const float* Rrow = R + ((size_t)(b * L + i)) * L * 64;
  for (int idx = tid; idx < 144 * 16; idx += 256) {
    int j = idx >> 4, d4 = (idx & 15) * 4;
    float4 r4 = *(const float4*)&Rrow[(size_t)j * 64 + d4];
    RlT[d4 + 0][j] = r4.x; RlT[d4 + 1][j] = r4.y;
    RlT[d4 + 2][j] = r4.z; RlT[d4 + 3][j] = r4.w;
  }
  if (tid < 128)
    *(float4*)&q8[tid * 4] =
        *(const float4*)&q[(size_t)(b * L + i) * 512 + tid * 4];
  __syncthreads();
  const float* kb = k + (size_t)b * L * 512;
  const int* mrow = msk + (size_t)(b * L + i) * 144;
  for (int idx = tid; idx < 8 * 144; idx += 256) {
    int h = idx / 144, j = idx - h * 144;
    const float* kr = kb + (size_t)j * 512 + h * 64;
    float s = 0.f;
#pragma unroll
    for (int d0 = 0; d0 < 64; d0 += 4) {
      float4 kv = *(const float4*)&kr[d0];
      s += q8[h * 64 + d0 + 0] * (kv.x + RlT[d0 + 0][j]);
      s += q8[h * 64 + d0 + 1] * (kv.y + RlT[d0 + 1][j]);
      s += q8[h * 64 + d0 + 2] * (kv.z + RlT[d0 + 2][j]);
      s += q8[h * 64 + d0 + 3] * (kv.w + RlT[d0 + 3][j]);
    }
    if (mrow[j] != 0) s = -1e18f;
    scl[h][j] = s;
  }
  __syncthreads();
  int h = tid >> 5, l = tid & 31;
  float m = -3.4e38f;
  for (int j = l; j < 144; j += 32) m = fmaxf(m, scl[h][j]);
#pragma unroll
  for (int mm = 16; mm >= 1; mm >>= 1) m = fmaxf(m, __shfl_xor(m, mm));
  float sum = 0.f;
  for (int j = l; j < 144; j += 32) {
    float p = __expf(scl[h][j] - m);
    scl[h][j] = p;
    sum += p;
  }
#pragma unroll
  for (int mm = 16; mm >= 1; mm >>= 1) sum += __shfl_xor(sum, mm);
  float inv = 1.f / sum;
  __syncthreads();
  int d0 = l * 2;
  float a0 = 0.f, a1 = 0.f;
  const float* vb = v + (size_t)b * L * 512 + h * 64 + d0;
  for (int j = 0; j < 144; ++j) {
    float p = scl[h][j];
    float2 vv = *(const float2*)&vb[(size_t)j * 512];
    a0 += p * (vv.x + RlT[d0][j]);
    a1 += p * (vv.y + RlT[d0 + 1][j]);
  }
  float2 o;
  o.x = a0 * inv;
  o.y = a1 * inv;
  *(float2*)&ctx_out[(size_t)(b * L + i) * 512 + h * 64 + d0] = o;
}

// ---------------- launch ----------------
extern "C" void kernel_launch(void* const* d_in, const int* in_sizes, int n_in,
                              void* d_out, int out_size, void* d_ws,
                              size_t ws_size, hipStream_t stream) {
  (void)in_sizes; (void)n_in; (void)out_size; (void)ws_size;
  const float* inputs = (const float*)d_in[0];
  const float* structure = (const float*)d_in[1];
  const int* mask = (const int*)d_in[2];
  const float* g_att = (const float*)d_in[3];
  const float* b_att = (const float*)d_in[4];
  const float* Wq = (const float*)d_in[5];
  const float* bq = (const float*)d_in[6];
  const float* Wk = (const float*)d_in[7];
  const float* bk = (const float*)d_in[8];
  const float* Wv = (const float*)d_in[9];
  const float* bv = (const float*)d_in[10];
  const float* Wo = (const float*)d_in[11];
  const float* bo = (const float*)d_in[12];
  const float* sWq = (const float*)d_in[13];
  const float* sbq = (const float*)d_in[14];
  const float* sWk = (const float*)d_in[15];
  const float* sbk = (const float*)d_in[16];
  const float* sWv = (const float*)d_in[17];
  const float* sbv = (const float*)d_in[18];
  const float* sWo = (const float*)d_in[19];
  const float* sbo = (const float*)d_in[20];
  const float* Wc = (const float*)d_in[21];
  const float* bc = (const float*)d_in[22];
  const float* g_s = (const float*)d_in[23];
  const float* b_s = (const float*)d_in[24];
  const float* g_ffn = (const float*)d_in[25];
  const float* b_ffn = (const float*)d_in[26];
  const float* W1 = (const float*)d_in[27];
  const float* b1 = (const float*)d_in[28];
  const float* W2 = (const float*)d_in[29];
  const float* b2 = (const float*)d_in[30];

  float* ws = (float*)d_ws;
  const size_t TOK = 2304ull * 512ull;
  float* xn = ws;            // x_norm, later ctx
  float* qw = xn + TOK;      // q, later x_norm2 (FFN)
  float* kw = qw + TOK;
  float* vw = kw + TOK;
  float* xw = vw + TOK;      // post-attention residual x
  float* Rw = xw + TOK;      // R [B,L,L,64], later FFN hidden
  float* C0w = Rw + 21233664ull;
  bf16_t* WT = (bf16_t*)(C0w + 64);   // [3][64][64] bf16
  bf16_t* M2T = WT + 12288;           // [64][256] bf16
  float* out = (float*)d_out;

  precompute<<<17, 256, 0, stream>>>(sWq, sWk, sWv, sWo, sbo, Wc, bc, WT, M2T,
                                     C0w);
  ln512<<<2304, 256, 0, stream>>>(inputs, g_att, b_att, xn);
  gemm_f32<<<dim3(8, 36), 256, 0, stream>>>(xn, Wq, bq, nullptr, qw, 2304, 512,
                                            512, 0.125f, 0);
  gemm_f32<<<dim3(8, 36), 256, 0, stream>>>(xn, Wk, bk, nullptr, kw, 2304, 512,
                                            512, 1.f, 0);
  gemm_f32<<<dim3(8, 36), 256, 0, stream>>>(xn, Wv, bv, nullptr, vw, 2304, 512,
                                            512, 1.f, 0);
  struct_mfma<<<10368, 256, 0, stream>>>(structure, WT, sbq, sbk, sbv, M2T,
                                         C0w, g_s, b_s, Rw);
  attn_main<<<2304, 256, 0, stream>>>(qw, kw, vw, Rw, mask, xn);
  gemm_f32<<<dim3(8, 36), 256, 0, stream>>>(xn, Wo, bo, inputs, xw, 2304, 512,
                                            512, 1.f, 0);
  ln512<<<2304, 256, 0, stream>>>(xw, g_ffn, b_ffn, qw);
  gemm_f32<<<dim3(32, 36), 256, 0, stream>>>(qw, W1, b1, nullptr, Rw, 2304,
                                             2048, 512, 1.f, 1);
  gemm_f32<<<dim3(8, 36), 256, 0, stream>>>(Rw, W2, b2, xw, out, 2304, 512,
                                            2048, 1.f, 0);
}

// Round 3
// 640.603 us; speedup vs baseline: 2.2259x; 1.2564x over previous
//
#include <hip/hip_runtime.h>
#include <math.h>

// B=16, L=144, D=512, H=8, DH=64, DS=64, HS=8, dsh=8, DFF=2048
// N = B*L*L = 331776 structure pairs

typedef __bf16 bf16_t;
typedef __bf16 bf16x8 __attribute__((ext_vector_type(8)));
typedef __bf16 bf16x2v __attribute__((ext_vector_type(2)));
typedef float f32x4 __attribute__((ext_vector_type(4)));

// ---------------- K0a: transpose+cvt all big weights to bf16 [N][K] ----------
__global__ __launch_bounds__(256) void transpose_all(
    const float* __restrict__ Wq, const float* __restrict__ Wk,
    const float* __restrict__ Wv, const float* __restrict__ Wo,
    const float* __restrict__ W1, const float* __restrict__ W2,
    bf16_t* __restrict__ WqkvT, bf16_t* __restrict__ WoT,
    bf16_t* __restrict__ W1T, bf16_t* __restrict__ W2T) {
  int bid = blockIdx.x;
  const float* W; bf16_t* WT; int K, N; float scale = 1.f; int tile;
  if (bid < 256)       { W = Wq; WT = WqkvT;            K = 512;  N = 512;  scale = 0.125f; tile = bid; }
  else if (bid < 512)  { W = Wk; WT = WqkvT + 262144;   K = 512;  N = 512;  tile = bid - 256; }
  else if (bid < 768)  { W = Wv; WT = WqkvT + 524288;   K = 512;  N = 512;  tile = bid - 512; }
  else if (bid < 1024) { W = Wo; WT = WoT;              K = 512;  N = 512;  tile = bid - 768; }
  else if (bid < 2048) { W = W1; WT = W1T;              K = 512;  N = 2048; tile = bid - 1024; }
  else                 { W = W2; WT = W2T;              K = 2048; N = 512;  tile = bid - 2048; }
  int ntn = N >> 5;
  int nb = (tile % ntn) * 32, kb = (tile / ntn) * 32;
  __shared__ float t32[32][33];
  int tx = threadIdx.x & 31, ty = threadIdx.x >> 5;
#pragma unroll
  for (int i = ty; i < 32; i += 8) t32[i][tx] = W[(size_t)(kb + i) * N + nb + tx];
  __syncthreads();
#pragma unroll
  for (int i = ty; i < 32; i += 8)
    WT[(size_t)(nb + i) * K + kb + tx] = (__bf16)(t32[tx][i] * scale);
}

// ---------------- K0b: small struct-weight precompute ----------------
// WT3[3][64][64]: (oc,ic) transposed sWq(*1/sqrt8)/sWk/sWv
// M2T[64][256]: M2T[o][t*64+e] = sum_c sWo[e,c]*Wc[o,c,t]
// C0[o] = bc[o] + sum_{t,c} sbo[c]*Wc[o,c,t]
// sbqkv[3][64], bqkv[1536]
__global__ __launch_bounds__(256) void precompute_misc(
    const float* __restrict__ sWq, const float* __restrict__ sWk,
    const float* __restrict__ sWv, const float* __restrict__ sWo,
    const float* __restrict__ sbq, const float* __restrict__ sbk,
    const float* __restrict__ sbv, const float* __restrict__ sbo,
    const float* __restrict__ Wc, const float* __restrict__ bc,
    const float* __restrict__ bq, const float* __restrict__ bk,
    const float* __restrict__ bv, bf16_t* __restrict__ WT3,
    bf16_t* __restrict__ M2T, float* __restrict__ C0,
    float* __restrict__ sbqkv, float* __restrict__ bqkv) {
  int blk = blockIdx.x, tid = threadIdx.x;
  if (blk == 16) {
    const float qs = 0.35355339059327373f;
    for (int idx = tid; idx < 4096; idx += 256) {
      int oc = idx >> 6, ic = idx & 63;
      WT3[idx] = (__bf16)(sWq[ic * 64 + oc] * qs);
      WT3[4096 + idx] = (__bf16)sWk[ic * 64 + oc];
      WT3[8192 + idx] = (__bf16)sWv[ic * 64 + oc];
    }
    if (tid < 64) {
      float s = bc[tid];
      for (int c = 0; c < 64; ++c) {
        float sb = sbo[c];
#pragma unroll
        for (int t = 0; t < 4; ++t) s += sb * Wc[tid * 256 + c * 4 + t];
      }
      C0[tid] = s;
      sbqkv[tid] = sbq[tid] * qs;
      sbqkv[64 + tid] = sbk[tid];
      sbqkv[128 + tid] = sbv[tid];
    }
  } else if (blk == 17) {
    for (int i = tid; i < 1536; i += 256)
      bqkv[i] = (i < 512) ? bq[i] * 0.125f
                          : ((i < 1024) ? bk[i - 512] : bv[i - 1024]);
  } else {
    int t = blk >> 2;
    int e = (blk & 3) * 16 + (tid >> 4);
    int o4 = (tid & 15) * 4;
    float acc[4] = {0.f, 0.f, 0.f, 0.f};
    for (int c = 0; c < 64; ++c) {
      float a = sWo[e * 64 + c];
#pragma unroll
      for (int j = 0; j < 4; ++j) acc[j] += a * Wc[(o4 + j) * 256 + c * 4 + t];
    }
#pragma unroll
    for (int j = 0; j < 4; ++j)
      M2T[(o4 + j) * 256 + t * 64 + e] = (__bf16)acc[j];
  }
}

// ---------------- K1: LayerNorm over 512 -> bf16 ----------------
__global__ __launch_bounds__(256) void ln512(
    const float* __restrict__ x, const float* __restrict__ g,
    const float* __restrict__ bb, bf16_t* __restrict__ out) {
  int row = blockIdx.x, tid = threadIdx.x;
  const float* xr = x + (size_t)row * 512;
  float2 v = *(const float2*)&xr[tid * 2];
  float s1 = v.x + v.y;
  float s2 = v.x * v.x + v.y * v.y;
#pragma unroll
  for (int m = 32; m >= 1; m >>= 1) {
    s1 += __shfl_xor(s1, m);
    s2 += __shfl_xor(s2, m);
  }
  __shared__ float red[8];
  int wid = tid >> 6;
  if ((tid & 63) == 0) { red[wid * 2] = s1; red[wid * 2 + 1] = s2; }
  __syncthreads();
  s1 = red[0] + red[2] + red[4] + red[6];
  s2 = red[1] + red[3] + red[5] + red[7];
  float mean = s1 * (1.f / 512.f);
  float var = s2 * (1.f / 512.f) - mean * mean;
  float rs = 1.f / sqrtf(var + 1e-6f);
  int c = tid * 2;
  float2 gg = *(const float2*)&g[c];
  float2 bv = *(const float2*)&bb[c];
  bf16x2v o;
  o[0] = (__bf16)((v.x - mean) * rs * gg.x + bv.x);
  o[1] = (__bf16)((v.y - mean) * rs * gg.y + bv.y);
  *(bf16x2v*)&out[(size_t)row * 512 + c] = o;
}

// ---------------- K2: bf16 MFMA GEMM ----------------
// C[M,N] = relu?(A[M,K]@B + bias) (+res) ; A bf16 row-major, BT bf16 [N][K]
// writes f32 Cf and/or bf16 Cb (either may be null)
__global__ __launch_bounds__(256) void gemm_bf16(
    const bf16_t* __restrict__ A, const bf16_t* __restrict__ BT,
    const float* __restrict__ bias, const float* __restrict__ res,
    float* __restrict__ Cf, bf16_t* __restrict__ Cb, int M, int N, int K,
    int relu) {
  int tid = threadIdx.x;
  int w = tid >> 6, l = tid & 63, l15 = l & 15, l4 = l >> 4;
  int n0 = blockIdx.x * 64, m0 = blockIdx.y * 64;
  int r = m0 + w * 16 + l15;
  const bf16_t* Arow = A + (size_t)r * K + l4 * 8;
  const bf16_t* Bbase = BT + (size_t)(n0 + l15) * K + l4 * 8;
  f32x4 acc[4];
#pragma unroll
  for (int ct = 0; ct < 4; ++ct) {
    float bv = bias[n0 + ct * 16 + l15];
    acc[ct] = (f32x4){bv, bv, bv, bv};
  }
#pragma unroll 4
  for (int k0 = 0; k0 < K; k0 += 32) {
    bf16x8 a8 = *(const bf16x8*)(Arow + k0);
#pragma unroll
    for (int ct = 0; ct < 4; ++ct) {
      bf16x8 b8 = *(const bf16x8*)(Bbase + (size_t)ct * 16 * K + k0);
      acc[ct] = __builtin_amdgcn_mfma_f32_16x16x32_bf16(a8, b8, acc[ct], 0, 0, 0);
    }
  }
#pragma unroll
  for (int ct = 0; ct < 4; ++ct) {
    int col = n0 + ct * 16 + l15;
#pragma unroll
    for (int i = 0; i < 4; ++i) {
      int row = m0 + w * 16 + l4 * 4 + i;
      float vv = acc[ct][i];
      if (relu) vv = fmaxf(vv, 0.f);
      if (res) vv += res[(size_t)row * N + col];
      if (Cf) Cf[(size_t)row * N + col] = vv;
      if (Cb) Cb[(size_t)row * N + col] = (__bf16)vv;
    }
  }
}

// ---------------- K3: MFMA structure pipeline v2 ----------------
// 32 pairs/block. QKV via MFMA -> bf16 LDS (pair-XOR-swizzled col blocks).
// Sub-attention: one thread per (pair,head), all in registers, exp w/o max.
// ctx overwrites Q region -> conv MFMA vs M2T -> ReLU -> LN(64) -> R (bf16).
__global__ __launch_bounds__(256) void struct_mfma(
    const float* __restrict__ S, const bf16_t* __restrict__ WT3,
    const float* __restrict__ sbqkv, const bf16_t* __restrict__ M2T,
    const float* __restrict__ C0, const float* __restrict__ gs,
    const float* __restrict__ bsv, bf16_t* __restrict__ Rout) {
  __shared__ bf16_t QL[8192];  // [p][t*64 + c'] ; later ctx ; 16KB
  __shared__ bf16_t KL[8192];  // later f32 cv[32][68]
  __shared__ bf16_t VL[8192];
  int tid = threadIdx.x;
  int w = tid >> 6, l = tid & 63, l15 = l & 15, l4 = l >> 4;
  int nb = blockIdx.x;
  int b = nb / 648;
  int p0 = (nb - b * 648) * 32;

  // ---- A-fragments direct from global: row r = w*32+rt*16+l15, k = kb*32+l4*8
  bf16x8 afr[2][2];
  const float* Sb = S + (size_t)p0 * 4096 + (size_t)b * 64;
#pragma unroll
  for (int rt = 0; rt < 2; ++rt)
#pragma unroll
    for (int kb = 0; kb < 2; ++kb) {
      int r = w * 32 + rt * 16 + l15;
      int k = kb * 32 + l4 * 8;
      const float* p = Sb + (size_t)r * 1024 + k;
      float4 u0 = *(const float4*)p;
      float4 u1 = *(const float4*)(p + 4);
      bf16x8 a;
      a[0] = (__bf16)u0.x; a[1] = (__bf16)u0.y;
      a[2] = (__bf16)u0.z; a[3] = (__bf16)u0.w;
      a[4] = (__bf16)u1.x; a[5] = (__bf16)u1.y;
      a[6] = (__bf16)u1.z; a[7] = (__bf16)u1.w;
      afr[rt][kb] = a;
    }

  // ---- QKV GEMMs, C-frags -> swizzled LDS
#pragma unroll 1
  for (int ct = 0; ct < 4; ++ct) {
    int col = ct * 16 + l15;
    f32x4 acc[3][2];
#pragma unroll
    for (int m = 0; m < 3; ++m) {
      float bv = sbqkv[m * 64 + col];
      acc[m][0] = (f32x4){bv, bv, bv, bv};
      acc[m][1] = (f32x4){bv, bv, bv, bv};
    }
#pragma unroll
    for (int kb = 0; kb < 2; ++kb) {
      int k = kb * 32 + l4 * 8;
#pragma unroll
      for (int m = 0; m < 3; ++m) {
        bf16x8 b8 = *(const bf16x8*)(WT3 + m * 4096 + col * 64 + k);
        acc[m][0] = __builtin_amdgcn_mfma_f32_16x16x32_bf16(afr[0][kb], b8,
                                                            acc[m][0], 0, 0, 0);
        acc[m][1] = __builtin_amdgcn_mfma_f32_16x16x32_bf16(afr[1][kb], b8,
                                                            acc[m][1], 0, 0, 0);
      }
    }
    int clo = l15 & 7;
    int cb = ct * 2 + (l15 >> 3);
#pragma unroll
    for (int rt = 0; rt < 2; ++rt) {
      int p = w * 8 + rt * 4 + l4;
      int base = p * 256 + (((cb ^ (p & 7)) << 3) | clo);
#pragma unroll
      for (int i = 0; i < 4; ++i) QL[base + i * 64] = (__bf16)acc[0][rt][i];
#pragma unroll
      for (int i = 0; i < 4; ++i) KL[base + i * 64] = (__bf16)acc[1][rt][i];
#pragma unroll
      for (int i = 0; i < 4; ++i) VL[base + i * 64] = (__bf16)acc[2][rt][i];
    }
  }
  __syncthreads();

  // ---- sub-attention: thread = (pair p, head h)
  {
    int p = tid >> 3, h = tid & 7;
    int co = ((h ^ (p & 7)) << 3);
    bf16x8 qv[4], kv[4], vv[4];
#pragma unroll
    for (int t = 0; t < 4; ++t) {
      qv[t] = *(const bf16x8*)&QL[p * 256 + t * 64 + co];
      kv[t] = *(const bf16x8*)&KL[p * 256 + t * 64 + co];
      vv[t] = *(const bf16x8*)&VL[p * 256 + t * 64 + co];
    }
    float qf[4][8];
#pragma unroll
    for (int t = 0; t < 4; ++t)
#pragma unroll
      for (int e = 0; e < 8; ++e) qf[t][e] = (float)qv[t][e];
    float P[4][4], rs[4] = {0.f, 0.f, 0.f, 0.f};
#pragma unroll
    for (int j = 0; j < 4; ++j) {
      float kf[8];
#pragma unroll
      for (int e = 0; e < 8; ++e) kf[e] = (float)kv[j][e];
#pragma unroll
      for (int i = 0; i < 4; ++i) {
        float s = 0.f;
#pragma unroll
        for (int e = 0; e < 8; ++e) s += qf[i][e] * kf[e];
        float ex = __expf(s);
        P[i][j] = ex;
        rs[i] += ex;
      }
    }
    float cx[4][8];
#pragma unroll
    for (int i = 0; i < 4; ++i)
#pragma unroll
      for (int e = 0; e < 8; ++e) cx[i][e] = 0.f;
#pragma unroll
    for (int j = 0; j < 4; ++j) {
      float vf[8];
#pragma unroll
      for (int e = 0; e < 8; ++e) vf[e] = (float)vv[j][e];
#pragma unroll
      for (int i = 0; i < 4; ++i)
#pragma unroll
        for (int e = 0; e < 8; ++e) cx[i][e] += P[i][j] * vf[e];
    }
#pragma unroll
    for (int i = 0; i < 4; ++i) {
      float inv = 1.f / rs[i];
      bf16x8 o;
#pragma unroll
      for (int e = 0; e < 8; ++e) o[e] = (__bf16)(cx[i][e] * inv);
      *(bf16x8*)&QL[p * 256 + i * 64 + co] = o;  // own q slot: no race
    }
  }
  __syncthreads();

  // ---- conv GEMM: rows = 32 pairs, K=256 (t*64+e), N=64 outputs
  int rtc = w >> 1;
  int ctb = (w & 1) * 2;
  f32x4 acc2[2];
#pragma unroll
  for (int c = 0; c < 2; ++c) {
    float c0v = C0[(ctb + c) * 16 + l15];
    acc2[c] = (f32x4){c0v, c0v, c0v, c0v};
  }
  int pr = rtc * 16 + l15, prl = pr & 7;
#pragma unroll
  for (int kb = 0; kb < 8; ++kb) {
    int k = kb * 32 + l4 * 8;
    int t = k >> 6, cb6 = (k >> 3) & 7;
    bf16x8 a2f = *(const bf16x8*)&QL[pr * 256 + t * 64 + ((cb6 ^ prl) << 3)];
#pragma unroll
    for (int c = 0; c < 2; ++c) {
      int o = (ctb + c) * 16 + l15;
      bf16x8 bm = *(const bf16x8*)(M2T + o * 256 + k);
      acc2[c] = __builtin_amdgcn_mfma_f32_16x16x32_bf16(a2f, bm, acc2[c], 0, 0, 0);
    }
  }
  __syncthreads();
  float* cv = (float*)KL;  // 32*68*4 = 8.7KB
#pragma unroll
  for (int c = 0; c < 2; ++c) {
    int o = (ctb + c) * 16 + l15;
#pragma unroll
    for (int j = 0; j < 4; ++j) {
      int pair = rtc * 16 + l4 * 4 + j;
      cv[pair * 68 + o] = fmaxf(acc2[c][j], 0.f);
    }
  }
  __syncthreads();

  // ---- LN(64) per pair: 8 lanes/pair, 8 ch/lane -> bf16 R
  int pair = tid >> 3, e8 = (tid & 7) * 8;
  float4 v0 = *(float4*)&cv[pair * 68 + e8];
  float4 v1 = *(float4*)&cv[pair * 68 + e8 + 4];
  float s1 = v0.x + v0.y + v0.z + v0.w + v1.x + v1.y + v1.z + v1.w;
  float s2 = v0.x * v0.x + v0.y * v0.y + v0.z * v0.z + v0.w * v0.w +
             v1.x * v1.x + v1.y * v1.y + v1.z * v1.z + v1.w * v1.w;
#pragma unroll
  for (int m = 1; m <= 4; m <<= 1) {
    s1 += __shfl_xor(s1, m);
    s2 += __shfl_xor(s2, m);
  }
  float mean = s1 * (1.f / 64.f);
  float var = s2 * (1.f / 64.f) - mean * mean;
  float rstd = 1.f / sqrtf(var + 1e-6f);
  float4 g0 = *(const float4*)&gs[e8], g1 = *(const float4*)&gs[e8 + 4];
  float4 b0 = *(const float4*)&bsv[e8], b1 = *(const float4*)&bsv[e8 + 4];
  bf16x8 ov;
  ov[0] = (__bf16)((v0.x - mean) * rstd * g0.x + b0.x);
  ov[1] = (__bf16)((v0.y - mean) * rstd * g0.y + b0.y);
  ov[2] = (__bf16)((v0.z - mean) * rstd * g0.z + b0.z);
  ov[3] = (__bf16)((v0.w - mean) * rstd * g0.w + b0.w);
  ov[4] = (__bf16)((v1.x - mean) * rstd * g1.x + b1.x);
  ov[5] = (__bf16)((v1.y - mean) * rstd * g1.y + b1.y);
  ov[6] = (__bf16)((v1.z - mean) * rstd * g1.z + b1.z);
  ov[7] = (__bf16)((v1.w - mean) * rstd * g1.w + b1.w);
  size_t base = ((size_t)b * 20736 + p0 + pair) * 64 + e8;
  *(bf16x8*)&Rout[base] = ov;
}

// ---------------- K4: relation-biased main attention ----------------
// qkv fused f32 [2304][1536]; R bf16; ctx out bf16
__global__ __launch_bounds__(256) void attn_main(
    const float* __restrict__ qkv, const bf16_t* __restrict__ R,
    const int* __restrict__ msk, bf16_t* __restrict__ ctx_out) {
  const int L = 144;
  int blk = blockIdx.x;
  int b = blk / L, i = blk - b * L;
  int tid = threadIdx.x;
  __shared__ float RlT[64][149];
  __shared__ float scl[8][144];
  __shared__ float q8[512];
  const bf16_t* Rrow = R + ((size_t)(b * L + i)) * L * 64;
  for (int idx = tid; idx < 144 * 8; idx += 256) {
    int j = idx >> 3, d8 = (idx & 7) * 8;
    bf16x8 r8 = *(const bf16x8*)&Rrow[(size_t)j * 64 + d8];
#pragma unroll
    for (int e = 0; e < 8; ++e) RlT[d8 + e][j] = (float)r8[e];
  }
  if (tid < 128)
    *(float4*)&q8[tid * 4] =
        *(const float4*)&qkv[(size_t)(b * L + i) * 1536 + tid * 4];
  __syncthreads();
  const float* kb = qkv + (size_t)b * L * 1536 + 512;
  const int* mrow = msk + (size_t)(b * L + i) * 144;
  for (int idx = tid; idx < 8 * 144; idx += 256) {
    int h = idx / 144, j = idx - h * 144;
    const float* kr = kb + (size_t)j * 1536 + h * 64;
    float s = 0.f;
#pragma unroll
    for (int d0 = 0; d0 < 64; d0 += 4) {
      float4 kv = *(const float4*)&kr[d0];
      s += q8[h * 64 + d0 + 0] * (kv.x + RlT[d0 + 0][j]);
      s += q8[h * 64 + d0 + 1] * (kv.y + RlT[d0 + 1][j]);
      s += q8[h * 64 + d0 + 2] * (kv.z + RlT[d0 + 2][j]);
      s += q8[h * 64 + d0 + 3] * (kv.w + RlT[d0 + 3][j]);
    }
    if (mrow[j] != 0) s = -1e18f;
    scl[h][j] = s;
  }
  __syncthreads();
  int h = tid >> 5, l = tid & 31;
  float m = -3.4e38f;
  for (int j = l; j < 144; j += 32) m = fmaxf(m, scl[h][j]);
#pragma unroll
  for (int mm = 16; mm >= 1; mm >>= 1) m = fmaxf(m, __shfl_xor(m, mm));
  float sum = 0.f;
  for (int j = l; j < 144; j += 32) {
    float p = __expf(scl[h][j] - m);
    scl[h][j] = p;
    sum += p;
  }
#pragma unroll
  for (int mm = 16; mm >= 1; mm >>= 1) sum += __shfl_xor(sum, mm);
  float inv = 1.f / sum;
  __syncthreads();
  int d0 = l * 2;
  float a0 = 0.f, a1 = 0.f;
  const float* vb = qkv + (size_t)b * L * 1536 + 1024 + h * 64 + d0;
  for (int j = 0; j < 144; ++j) {
    float p = scl[h][j];
    float2 vv = *(const float2*)&vb[(size_t)j * 1536];
    a0 += p * (vv.x + RlT[d0][j]);
    a1 += p * (vv.y + RlT[d0 + 1][j]);
  }
  bf16x2v o;
  o[0] = (__bf16)(a0 * inv);
  o[1] = (__bf16)(a1 * inv);
  *(bf16x2v*)&ctx_out[(size_t)(b * L + i) * 512 + h * 64 + d0] = o;
}

// ---------------- launch ----------------
extern "C" void kernel_launch(void* const* d_in, const int* in_sizes, int n_in,
                              void* d_out, int out_size, void* d_ws,
                              size_t ws_size, hipStream_t stream) {
  (void)in_sizes; (void)n_in; (void)out_size; (void)ws_size;
  const float* inputs = (const float*)d_in[0];
  const float* structure = (const float*)d_in[1];
  const int* mask = (const int*)d_in[2];
  const float* g_att = (const float*)d_in[3];
  const float* b_att = (const float*)d_in[4];
  const float* Wq = (const float*)d_in[5];
  const float* bq = (const float*)d_in[6];
  const float* Wk = (const float*)d_in[7];
  const float* bk = (const float*)d_in[8];
  const float* Wv = (const float*)d_in[9];
  const float* bv = (const float*)d_in[10];
  const float* Wo = (const float*)d_in[11];
  const float* bo = (const float*)d_in[12];
  const float* sWq = (const float*)d_in[13];
  const float* sbq = (const float*)d_in[14];
  const float* sWk = (const float*)d_in[15];
  const float* sbk = (const float*)d_in[16];
  const float* sWv = (const float*)d_in[17];
  const float* sbv = (const float*)d_in[18];
  const float* sWo = (const float*)d_in[19];
  const float* sbo = (const float*)d_in[20];
  const float* Wc = (const float*)d_in[21];
  const float* bc = (const float*)d_in[22];
  const float* g_s = (const float*)d_in[23];
  const float* b_s = (const float*)d_in[24];
  const float* g_ffn = (const float*)d_in[25];
  const float* b_ffn = (const float*)d_in[26];
  const float* W1 = (const float*)d_in[27];
  const float* b1 = (const float*)d_in[28];
  const float* W2 = (const float*)d_in[29];
  const float* b2 = (const float*)d_in[30];

  char* base = (char*)d_ws;
  bf16_t* Rw = (bf16_t*)base;                       // 42,467,328 B
  float* qkvw = (float*)(base + 42467328);          // 14,155,776 B
  float* xw = (float*)(base + 56623104);            // 4,718,592 B
  bf16_t* xnb = (bf16_t*)(base + 61341696);         // 2,359,296 B
  bf16_t* ctxb = (bf16_t*)(base + 63700992);        // 2,359,296 B
  bf16_t* WqkvT = (bf16_t*)(base + 66060288);       // 1,572,864 B
  bf16_t* WoT = (bf16_t*)(base + 67633152);         // 524,288 B
  bf16_t* W1T = (bf16_t*)(base + 68157440);         // 2,097,152 B
  bf16_t* W2T = (bf16_t*)(base + 70254592);         // 2,097,152 B
  bf16_t* WT3 = (bf16_t*)(base + 72351744);         // 24,576 B
  bf16_t* M2T = (bf16_t*)(base + 72376320);         // 32,768 B
  float* C0w = (float*)(base + 72409088);           // 256 B
  float* sbqkv = (float*)(base + 72409344);         // 768 B
  float* bqkv = (float*)(base + 72410112);          // 6,144 B
  bf16_t* hb = (bf16_t*)qkvw;  // FFN hidden aliases dead qkv (9.4MB < 14.2MB)
  float* out = (float*)d_out;

  transpose_all<<<3072, 256, 0, stream>>>(Wq, Wk, Wv, Wo, W1, W2, WqkvT, WoT,
                                          W1T, W2T);
  precompute_misc<<<18, 256, 0, stream>>>(sWq, sWk, sWv, sWo, sbq, sbk, sbv,
                                          sbo, Wc, bc, bq, bk, bv, WT3, M2T,
                                          C0w, sbqkv, bqkv);
  ln512<<<2304, 256, 0, stream>>>(inputs, g_att, b_att, xnb);
  gemm_bf16<<<dim3(24, 36), 256, 0, stream>>>(xnb, WqkvT, bqkv, nullptr, qkvw,
                                              nullptr, 2304, 1536, 512, 0);
  struct_mfma<<<10368, 256, 0, stream>>>(structure, WT3, sbqkv, M2T, C0w, g_s,
                                         b_s, Rw);
  attn_main<<<2304, 256, 0, stream>>>(qkvw, Rw, mask, ctxb);
  gemm_bf16<<<dim3(8, 36), 256, 0, stream>>>(ctxb, WoT, bo, inputs, xw,
                                             nullptr, 2304, 512, 512, 0);
  ln512<<<2304, 256, 0, stream>>>(xw, g_ffn, b_ffn, xnb);
  gemm_bf16<<<dim3(32, 36), 256, 0, stream>>>(xnb, W1T, b1, nullptr, nullptr,
                                              hb, 2304, 2048, 512, 1);
  gemm_bf16<<<dim3(8, 36), 256, 0, stream>>>(hb, W2T, b2, xw, out, nullptr,
                                             2304, 512, 2048, 0);
}